// Round 1
// baseline (1448.939 us; speedup 1.0000x reference)
//
#include <hip/hip_runtime.h>
#include <hip/hip_bf16.h>
#include <stdint.h>

typedef __attribute__((ext_vector_type(8))) short short8;
typedef __attribute__((ext_vector_type(4))) float f32x4;

__device__ __forceinline__ unsigned f2bf(float f) {
  union { float f; unsigned u; } v; v.f = f;
  return (v.u + 0x7FFFu + ((v.u >> 16) & 1u)) >> 16;   // RNE
}
__device__ __forceinline__ unsigned pk2(float a, float b) {
  return f2bf(a) | (f2bf(b) << 16);
}

// ---------------- f32 -> bf16 convert, 8 elems/thread, grid-stride ----------
__global__ __launch_bounds__(256) void cvt_bf16(const float* __restrict__ in,
                                                uint32_t* __restrict__ out,
                                                long n8) {
  long i = (long)blockIdx.x * 256 + threadIdx.x;
  long stride = (long)gridDim.x * 256;
  for (; i < n8; i += stride) {
    const float4* p = reinterpret_cast<const float4*>(in + i * 8);
    float4 a = p[0], b = p[1];
    uint4 v;
    v.x = pk2(a.x, a.y); v.y = pk2(a.z, a.w);
    v.z = pk2(b.x, b.y); v.w = pk2(b.z, b.w);
    reinterpret_cast<uint4*>(out)[i] = v;
  }
}

// ---------------- fused MFMA GEMM -------------------------------------------
// C-tile = A[128 rows x K] @ B[N x K]^T tile (128 cols), bf16 MFMA 16x16x32.
// A row gr -> element offset (gr/tdA)*asB + (gr%tdA)*asT  (covers strided hs).
// EPI: 0 = store (+bias), 1 = accumulate into C (+bias),
//      2 = score: s[row] += sum_col tanh(acc + v1[b][col]) * w2[col]  (atomic)
template<int EPI, bool ABF, bool BBF>
__global__ __launch_bounds__(256) void mfma_gemm(
    const void* __restrict__ Ap, const void* __restrict__ Bp,
    float* __restrict__ C, int N, int K,
    int tdA, long asB, long asT, int ldb,
    const float* __restrict__ bias, int ldc, int coff,
    int tdE, const float* __restrict__ v1, int ldv1,
    const float* __restrict__ w2, float* __restrict__ score)
{
  __shared__ char lds[16384];               // A: [0,8K) B: [8K,16K)
  const int tid = threadIdx.x;
  const int m0 = blockIdx.y * 128;
  const int n0 = blockIdx.x * 128;

  // staging assignment: slot s in {tid, tid+256}; row = s>>2 (0..127), j = s&3
  const int rowL = tid >> 2;                // 0..63  (second slot: +64)
  const int j = tid & 3;
  long aoff[2]; long boff[2]; bool bok[2];
  {
    int g0 = m0 + rowL, g1 = g0 + 64;
    aoff[0] = (long)(g0 / tdA) * asB + (long)(g0 % tdA) * asT;
    aoff[1] = (long)(g1 / tdA) * asB + (long)(g1 % tdA) * asT;
    int nb0 = n0 + rowL, nb1 = nb0 + 64;
    boff[0] = (long)nb0 * ldb; bok[0] = nb0 < N;
    boff[1] = (long)nb1 * ldb; bok[1] = nb1 < N;
  }
  // LDS byte dst: row*64 + (slot ^ (row&3))*16   ((row+64)&3 == row&3)
  const int dst0 = rowL * 64 + ((j ^ (rowL & 3)) << 4);

  const int wv = tid >> 6;
  const int lane = tid & 63;
  const int wm = (wv >> 1) * 64;
  const int wn = (wv & 1) * 64;
  const int l15 = lane & 15;
  const int lg = lane >> 4;

  f32x4 acc[4][4];
  #pragma unroll
  for (int a = 0; a < 4; ++a)
    #pragma unroll
    for (int b = 0; b < 4; ++b) acc[a][b] = f32x4{0.f, 0.f, 0.f, 0.f};

  for (int k0 = 0; k0 < K; k0 += 32) {
    #pragma unroll
    for (int h = 0; h < 2; ++h) {
      char* da = &lds[dst0 + h * 4096];
      if (ABF) {
        const uint16_t* p = (const uint16_t*)Ap + aoff[h] + k0 + j * 8;
        *(uint4*)da = *(const uint4*)p;
      } else {
        const float* p = (const float*)Ap + aoff[h] + k0 + j * 8;
        float4 x = ((const float4*)p)[0];
        float4 y = ((const float4*)p)[1];
        uint4 v; v.x = pk2(x.x, x.y); v.y = pk2(x.z, x.w);
        v.z = pk2(y.x, y.y); v.w = pk2(y.z, y.w);
        *(uint4*)da = v;
      }
      char* db = &lds[8192 + dst0 + h * 4096];
      if (!bok[h]) {
        *(uint4*)db = make_uint4(0u, 0u, 0u, 0u);
      } else if (BBF) {
        const uint16_t* p = (const uint16_t*)Bp + boff[h] + k0 + j * 8;
        *(uint4*)db = *(const uint4*)p;
      } else {
        const float* p = (const float*)Bp + boff[h] + k0 + j * 8;
        float4 x = ((const float4*)p)[0];
        float4 y = ((const float4*)p)[1];
        uint4 v; v.x = pk2(x.x, x.y); v.y = pk2(x.z, x.w);
        v.z = pk2(y.x, y.y); v.w = pk2(y.z, y.w);
        *(uint4*)db = v;
      }
    }
    __syncthreads();
    short8 af[4], bfr[4];
    #pragma unroll
    for (int mi = 0; mi < 4; ++mi) {
      int r = wm + mi * 16 + l15;
      af[mi] = *(const short8*)&lds[r * 64 + ((lg ^ (r & 3)) << 4)];
    }
    #pragma unroll
    for (int ni = 0; ni < 4; ++ni) {
      int r = wn + ni * 16 + l15;
      bfr[ni] = *(const short8*)&lds[8192 + r * 64 + ((lg ^ (r & 3)) << 4)];
    }
    #pragma unroll
    for (int mi = 0; mi < 4; ++mi)
      #pragma unroll
      for (int ni = 0; ni < 4; ++ni)
        acc[mi][ni] = __builtin_amdgcn_mfma_f32_16x16x32_bf16(
            af[mi], bfr[ni], acc[mi][ni], 0, 0, 0);
    __syncthreads();
  }

  if (EPI == 2) {
    #pragma unroll
    for (int mi = 0; mi < 4; ++mi) {
      #pragma unroll
      for (int r = 0; r < 4; ++r) {
        int grow = m0 + wm + mi * 16 + lg * 4 + r;
        int bb = grow / tdE;
        float s = 0.f;
        #pragma unroll
        for (int ni = 0; ni < 4; ++ni) {
          int col = n0 + wn + ni * 16 + l15;
          float val = acc[mi][ni][r] + v1[(long)bb * ldv1 + col];
          s += tanhf(val) * w2[col];
        }
        s += __shfl_xor(s, 1, 16);
        s += __shfl_xor(s, 2, 16);
        s += __shfl_xor(s, 4, 16);
        s += __shfl_xor(s, 8, 16);
        if (l15 == 0) atomicAdd(score + grow, s);
      }
    }
  } else {
    #pragma unroll
    for (int mi = 0; mi < 4; ++mi)
      #pragma unroll
      for (int ni = 0; ni < 4; ++ni)
        #pragma unroll
        for (int r = 0; r < 4; ++r) {
          int col = n0 + wn + ni * 16 + l15;
          if (col < N) {
            int grow = m0 + wm + mi * 16 + lg * 4 + r;
            float v = acc[mi][ni][r];
            if (bias) v += bias[col];
            float* cp = C + (long)grow * ldc + coff + col;
            if (EPI == 1) v += *cp;
            *cp = v;
          }
        }
  }
}

// ---------------- softmax over T + weighted sum over vec2 (D=1024) ----------
__global__ __launch_bounds__(256) void softmax_ctx(
    const float* __restrict__ score, int Tdim,
    const float* __restrict__ vec2, long sB, long sT,
    float* __restrict__ out)
{
  __shared__ float ex[128];
  int b = blockIdx.x, tid = threadIdx.x;
  if (tid < Tdim) ex[tid] = score[(long)b * Tdim + tid];
  __syncthreads();
  float mx = -1e30f;
  for (int t = 0; t < Tdim; ++t) mx = fmaxf(mx, ex[t]);
  float myex = 0.f;
  if (tid < Tdim) myex = expf(ex[tid] - mx);
  __syncthreads();
  if (tid < Tdim) ex[tid] = myex;
  __syncthreads();
  float sum = 0.f;
  for (int t = 0; t < Tdim; ++t) sum += ex[t];
  float inv = 1.f / sum;
  int d = tid * 4;
  float ax = 0.f, ay = 0.f, az = 0.f, aw = 0.f;
  const float* base = vec2 + (long)b * sB + d;
  for (int t = 0; t < Tdim; ++t) {
    float4 v = *(const float4*)(base + (long)t * sT);
    float w = ex[t];
    ax += w * v.x; ay += w * v.y; az += w * v.z; aw += w * v.w;
  }
  float4 r; r.x = ax * inv; r.y = ay * inv; r.z = az * inv; r.w = aw * inv;
  *(float4*)&out[(long)b * 1024 + d] = r;
}

// ---------------- final attention (T=3) + build x = [final_ctx, input] ------
__global__ __launch_bounds__(256) void final_ctx_x(
    const float* __restrict__ s3, const float* __restrict__ cs,
    const float* __restrict__ input, float* __restrict__ ofc,
    float* __restrict__ x)
{
  int b = blockIdx.x, tid = threadIdx.x;
  float s0 = s3[b * 3], s1 = s3[b * 3 + 1], s2 = s3[b * 3 + 2];
  float mx = fmaxf(s0, fmaxf(s1, s2));
  float e0 = expf(s0 - mx), e1 = expf(s1 - mx), e2 = expf(s2 - mx);
  float inv = 1.f / (e0 + e1 + e2);
  e0 *= inv; e1 *= inv; e2 *= inv;
  if (tid < 128) {
    int d = tid * 4;
    const float* c = cs + (long)b * 1536 + d;
    float4 v0 = *(const float4*)(c);
    float4 v1 = *(const float4*)(c + 512);
    float4 v2 = *(const float4*)(c + 1024);
    float4 r;
    r.x = e0 * v0.x + e1 * v1.x + e2 * v2.x;
    r.y = e0 * v0.y + e1 * v1.y + e2 * v2.y;
    r.z = e0 * v0.z + e1 * v1.z + e2 * v2.z;
    r.w = e0 * v0.w + e1 * v1.w + e2 * v2.w;
    *(float4*)&ofc[(long)b * 512 + d] = r;
    *(float4*)&x[(long)b * 1536 + d] = r;
  }
  int d2 = tid * 4;
  float4 iv = *(const float4*)&input[(long)b * 1024 + d2];
  *(float4*)&x[(long)b * 1536 + 512 + d2] = iv;
}

// ---------------- LSTM pointwise --------------------------------------------
__global__ __launch_bounds__(256) void lstm_kernel(
    const float* __restrict__ gates, const float* __restrict__ cprev,
    float* __restrict__ hout, float* __restrict__ cout,
    float* __restrict__ hws)
{
  int idx = blockIdx.x * 256 + threadIdx.x;
  int b = idx >> 10, jj = idx & 1023;
  const float* g = gates + (long)b * 4096;
  float gi = g[jj], gf = g[1024 + jj], gg = g[2048 + jj], go = g[3072 + jj];
  float i = 1.f / (1.f + expf(-gi));
  float f = 1.f / (1.f + expf(-gf));
  float t = tanhf(gg);
  float o = 1.f / (1.f + expf(-go));
  float c = f * cprev[idx] + i * t;
  float h = o * tanhf(c);
  hout[idx] = h; cout[idx] = c; hws[idx] = h;
}

// ---------------- host ------------------------------------------------------
extern "C" void kernel_launch(void* const* d_in, const int* in_sizes, int n_in,
                              void* d_out, int out_size, void* d_ws, size_t ws_size,
                              hipStream_t stream) {
  const float* input   = (const float*)d_in[0];
  const float* visual  = (const float*)d_in[1];
  const float* audio   = (const float*)d_in[2];
  const float* hstates = (const float*)d_in[3];
  const float* cell    = (const float*)d_in[4];
  const float* ctxq    = (const float*)d_in[5];
  const float* Wv0 = (const float*)d_in[6],  *Wv1 = (const float*)d_in[7],  *Wv2 = (const float*)d_in[8];
  const float* Wa0 = (const float*)d_in[9],  *Wa1 = (const float*)d_in[10], *Wa2 = (const float*)d_in[11];
  const float* Wh0 = (const float*)d_in[12], *Wh1 = (const float*)d_in[13], *Wh2 = (const float*)d_in[14];
  const float* Wc0 = (const float*)d_in[15], *Wc1 = (const float*)d_in[16], *Wc2 = (const float*)d_in[17];
  const float* Wac = (const float*)d_in[18], *bac = (const float*)d_in[19];
  const float* Wvc = (const float*)d_in[20], *bvc = (const float*)d_in[21];
  const float* Whc = (const float*)d_in[22], *bhc = (const float*)d_in[23];
  const float* W_ih = (const float*)d_in[24], *W_hh = (const float*)d_in[25];
  const float* b_ih = (const float*)d_in[26], *b_hh = (const float*)d_in[27];
  const float* W_out = (const float*)d_in[28], *b_out = (const float*)d_in[29];

  float* out = (float*)d_out;
  const long OFF_H = 2560000, OFF_C = 2691072, OFF_FC = 2822144;

  // ---- carve workspace (small buffers first; bf16 copies if they fit) ----
  char* cur = (char*)d_ws;
  auto alloc = [&](size_t n) { char* p = cur; cur += (n + 255) & ~(size_t)255; return p; };
  float* scoreV = (float*)alloc(16384 * 4);
  float* scoreA = (float*)alloc(16384 * 4);
  float* scoreH = (float*)alloc(2048 * 4);
  float* scoreC = (float*)alloc(384 * 4);
  float* v1v  = (float*)alloc(128 * 1024 * 4);
  float* v1a  = (float*)alloc(128 * 1024 * 4);
  float* v1h  = (float*)alloc(128 * 1024 * 4);
  float* ctxV = (float*)alloc(128 * 1024 * 4);
  float* ctxA = (float*)alloc(128 * 1024 * 4);
  float* ctxH = (float*)alloc(128 * 1024 * 4);
  float* cstack = (float*)alloc(128 * 3 * 512 * 4);
  float* v1c  = (float*)alloc(128 * 512 * 4);
  float* xbuf = (float*)alloc(128 * 1536 * 4);
  float* gates = (float*)alloc(128 * 4096 * 4);
  float* hnew = (float*)alloc(128 * 1024 * 4);
  size_t small_used = (size_t)(cur - (char*)d_ws);
  size_t big_need = (size_t)(16777216 + 16777216 + 2097152 + 1048576 * 3) * 2 + 4096;
  bool big = ws_size >= small_used + big_need;
  uint16_t *visB = nullptr, *audB = nullptr, *hsB = nullptr,
           *wv1B = nullptr, *wa1B = nullptr, *wh1B = nullptr;
  if (big) {
    visB = (uint16_t*)alloc(16777216 * 2);
    audB = (uint16_t*)alloc(16777216 * 2);
    hsB  = (uint16_t*)alloc(2097152 * 2);
    wv1B = (uint16_t*)alloc(1048576 * 2);
    wa1B = (uint16_t*)alloc(1048576 * 2);
    wh1B = (uint16_t*)alloc(1048576 * 2);
  }

  // ---- converts ----
  if (big) {
    cvt_bf16<<<2048, 256, 0, stream>>>(visual, (uint32_t*)visB, 16777216 / 8);
    cvt_bf16<<<2048, 256, 0, stream>>>(audio, (uint32_t*)audB, 16777216 / 8);
    cvt_bf16<<<1024, 256, 0, stream>>>(hstates, (uint32_t*)hsB, 2097152 / 8);
    cvt_bf16<<<512, 256, 0, stream>>>(Wv1, (uint32_t*)wv1B, 1048576 / 8);
    cvt_bf16<<<512, 256, 0, stream>>>(Wa1, (uint32_t*)wa1B, 1048576 / 8);
    cvt_bf16<<<512, 256, 0, stream>>>(Wh1, (uint32_t*)wh1B, 1048576 / 8);
  }
  hipMemsetAsync(scoreV, 0, (16384 + 16384 + 2048 + 384) * 4, stream);

  // ---- v1 = q @ W0^T  (q = context[:,0,:], [128,512]) ----
  mfma_gemm<0, false, false><<<dim3(8, 1), 256, 0, stream>>>(
      ctxq, Wv0, v1v, 1024, 512, 1, 512, 0, 512, nullptr, 1024, 0, 1, nullptr, 0, nullptr, nullptr);
  mfma_gemm<0, false, false><<<dim3(8, 1), 256, 0, stream>>>(
      ctxq, Wa0, v1a, 1024, 512, 1, 512, 0, 512, nullptr, 1024, 0, 1, nullptr, 0, nullptr, nullptr);
  mfma_gemm<0, false, false><<<dim3(8, 1), 256, 0, stream>>>(
      ctxq, Wh0, v1h, 1024, 512, 1, 512, 0, 512, nullptr, 1024, 0, 1, nullptr, 0, nullptr, nullptr);

  // ---- fused score GEMMs ----
  if (big) {
    mfma_gemm<2, true, true><<<dim3(8, 128), 256, 0, stream>>>(
        visB, wv1B, nullptr, 1024, 1024, 1, 1024, 0, 1024, nullptr, 0, 0,
        128, v1v, 1024, Wv2, scoreV);
    mfma_gemm<2, true, true><<<dim3(8, 128), 256, 0, stream>>>(
        audB, wa1B, nullptr, 1024, 1024, 1, 1024, 0, 1024, nullptr, 0, 0,
        128, v1a, 1024, Wa2, scoreA);
    mfma_gemm<2, true, true><<<dim3(8, 16), 256, 0, stream>>>(
        hsB, wh1B, nullptr, 1024, 1024, 16, 1024, 131072, 1024, nullptr, 0, 0,
        16, v1h, 1024, Wh2, scoreH);
  } else {
    mfma_gemm<2, false, false><<<dim3(8, 128), 256, 0, stream>>>(
        visual, Wv1, nullptr, 1024, 1024, 1, 1024, 0, 1024, nullptr, 0, 0,
        128, v1v, 1024, Wv2, scoreV);
    mfma_gemm<2, false, false><<<dim3(8, 128), 256, 0, stream>>>(
        audio, Wa1, nullptr, 1024, 1024, 1, 1024, 0, 1024, nullptr, 0, 0,
        128, v1a, 1024, Wa2, scoreA);
    mfma_gemm<2, false, false><<<dim3(8, 16), 256, 0, stream>>>(
        hstates, Wh1, nullptr, 1024, 1024, 16, 1024, 131072, 1024, nullptr, 0, 0,
        16, v1h, 1024, Wh2, scoreH);
  }

  // ---- softmax + context ----
  softmax_ctx<<<128, 256, 0, stream>>>(scoreV, 128, visual, 131072, 1024, ctxV);
  softmax_ctx<<<128, 256, 0, stream>>>(scoreA, 128, audio, 131072, 1024, ctxA);
  softmax_ctx<<<128, 256, 0, stream>>>(scoreH, 16, hstates, 1024, 131072, ctxH);

  // ---- context_stack = [audio, visual, hidden] projections (+bias) ----
  mfma_gemm<0, false, false><<<dim3(4, 1), 256, 0, stream>>>(
      ctxA, Wac, cstack, 512, 1024, 1, 1024, 0, 1024, bac, 1536, 0, 1, nullptr, 0, nullptr, nullptr);
  mfma_gemm<0, false, false><<<dim3(4, 1), 256, 0, stream>>>(
      ctxV, Wvc, cstack, 512, 1024, 1, 1024, 0, 1024, bvc, 1536, 512, 1, nullptr, 0, nullptr, nullptr);
  mfma_gemm<0, false, false><<<dim3(4, 1), 256, 0, stream>>>(
      ctxH, Whc, cstack, 512, 1024, 1, 1024, 0, 1024, bhc, 1536, 1024, 1, nullptr, 0, nullptr, nullptr);

  // ---- final attention ----
  const float* hid_last = hstates + (long)15 * 128 * 1024;
  mfma_gemm<0, false, false><<<dim3(4, 1), 256, 0, stream>>>(
      hid_last, Wc0, v1c, 512, 1024, 1, 1024, 0, 1024, nullptr, 512, 0, 1, nullptr, 0, nullptr, nullptr);
  mfma_gemm<2, false, false><<<dim3(4, 3), 256, 0, stream>>>(
      cstack, Wc1, nullptr, 512, 512, 1, 512, 0, 512, nullptr, 0, 0,
      3, v1c, 512, Wc2, scoreC);
  final_ctx_x<<<128, 256, 0, stream>>>(scoreC, cstack, input, out + OFF_FC, xbuf);

  // ---- LSTM gates ----
  mfma_gemm<0, false, false><<<dim3(32, 1), 256, 0, stream>>>(
      xbuf, W_ih, gates, 4096, 1536, 1, 1536, 0, 1536, b_ih, 4096, 0, 1, nullptr, 0, nullptr, nullptr);
  mfma_gemm<1, false, false><<<dim3(32, 1), 256, 0, stream>>>(
      hid_last, W_hh, gates, 4096, 1024, 1, 1024, 0, 1024, b_hh, 4096, 0, 1, nullptr, 0, nullptr, nullptr);
  lstm_kernel<<<512, 256, 0, stream>>>(gates, cell, out + OFF_H, out + OFF_C, hnew);

  // ---- logits ----
  mfma_gemm<0, false, false><<<dim3(157, 1), 256, 0, stream>>>(
      hnew, W_out, out, 20000, 1024, 1, 1024, 0, 1024, b_out, 20000, 0, 1, nullptr, 0, nullptr, nullptr);

  (void)in_sizes; (void)n_in; (void)out_size;
}

// Round 2
// 870.769 us; speedup vs baseline: 1.6640x; 1.6640x over previous
//
#include <hip/hip_runtime.h>
#include <hip/hip_bf16.h>
#include <stdint.h>

typedef __attribute__((ext_vector_type(8))) short short8;
typedef __attribute__((ext_vector_type(4))) float f32x4;

__device__ __forceinline__ unsigned f2bf(float f) {
  union { float f; unsigned u; } v; v.f = f;
  return (v.u + 0x7FFFu + ((v.u >> 16) & 1u)) >> 16;   // RNE
}
__device__ __forceinline__ unsigned pk2(float a, float b) {
  return f2bf(a) | (f2bf(b) << 16);
}
__device__ __forceinline__ float bf2f(uint16_t u) {
  union { unsigned u; float f; } v; v.u = ((unsigned)u) << 16; return v.f;
}
__device__ __forceinline__ void gload_lds16(const void* g, void* l) {
  __builtin_amdgcn_global_load_lds(
      (const __attribute__((address_space(1))) void*)g,
      (__attribute__((address_space(3))) void*)l, 16, 0, 0);
}

// ---------------- multi-segment f32 -> bf16 convert -------------------------
struct CvtBatch { const float* in[6]; uint16_t* out[6]; long cum[7]; };
__global__ __launch_bounds__(256) void cvt_multi(CvtBatch cb, long total8) {
  long i = (long)blockIdx.x * 256 + threadIdx.x;
  long stride = (long)gridDim.x * 256;
  for (; i < total8; i += stride) {
    int s = 0;
    while (i >= cb.cum[s + 1]) ++s;
    long li = i - cb.cum[s];
    const float4* p = reinterpret_cast<const float4*>(cb.in[s] + li * 8);
    float4 a = p[0], b = p[1];
    uint4 v;
    v.x = pk2(a.x, a.y); v.y = pk2(a.z, a.w);
    v.z = pk2(b.x, b.y); v.w = pk2(b.z, b.w);
    reinterpret_cast<uint4*>(cb.out[s])[li] = v;
  }
}

// ---------------- batched, pipelined 128x128xBK64 MFMA GEMM -----------------
// EPI 0: C[row, coff+col] = acc + bias[col] + bias2[col]
// EPI 2: score[row] += sum_col tanh(acc + v1[row/tdE][col]) * w2[col]
// STG 0: A,B f32, reg-staged + converted; B split at kcut -> B2
// STG 1: A,B bf16, global_load_lds direct
struct GemmDesc {
  const void* A; const void* B; const void* B2;
  float* C; const float* bias; const float* bias2;
  const float* v1; const float* w2; float* score;
  int N, K, kcut, ldb, ldb2, ldc, coff, ldv1, tdE, tdA;
  long asB, asT;
};
struct GemmBatch { GemmDesc d[3]; };

template<int EPI, int STG>
__global__ __launch_bounds__(256) void gemm2(GemmBatch batch) {
  const GemmDesc g = batch.d[blockIdx.z];
  __shared__ char lds[2][32768];           // per buf: A [0,16K) B [16K,32K)
  const int tid = threadIdx.x;
  const int m0 = blockIdx.y * 128;
  const int n0 = blockIdx.x * 128;

  // staging geometry: slot s = tid + i*256 -> row = s>>3 (0..127), chunk = s&7
  const int rbase = tid >> 3;                       // 0..31, rows rbase+i*32
  const int cswz = (tid & 7) ^ (rbase & 7);         // swizzled source chunk
  const int dstA = tid * 16;                        // + i*4096, linear LDS dst
  long aoffE[4]; int brow[4]; bool bok[4];
  #pragma unroll
  for (int i = 0; i < 4; ++i) {
    int ar = m0 + rbase + i * 32;
    aoffE[i] = (long)(ar / g.tdA) * g.asB + (long)(ar % g.tdA) * g.asT + cswz * 8;
    int br = n0 + rbase + i * 32;
    brow[i] = br; bok[i] = br < g.N;
  }

  // wave / fragment geometry
  const int wv = tid >> 6, lane = tid & 63;
  const int wm = (wv >> 1) * 64, wn = (wv & 1) * 64;
  const int l15 = lane & 15, lg = lane >> 4;
  int raddr[4][2], baddr[4][2];
  #pragma unroll
  for (int q = 0; q < 4; ++q) {
    int rA = wm + q * 16 + l15;
    int rB = wn + q * 16 + l15;
    #pragma unroll
    for (int kk = 0; kk < 2; ++kk) {
      raddr[q][kk] = rA * 128 + (((kk * 4 + lg) ^ (rA & 7)) << 4);
      baddr[q][kk] = 16384 + rB * 128 + (((kk * 4 + lg) ^ (rB & 7)) << 4);
    }
  }

  f32x4 acc[4][4];
  #pragma unroll
  for (int a = 0; a < 4; ++a)
    #pragma unroll
    for (int b = 0; b < 4; ++b) acc[a][b] = f32x4{0.f, 0.f, 0.f, 0.f};

  const int nt = g.K >> 6;

  float4 ra[4][2], rb[4][2];
  auto loadR = [&](int k0) {
    #pragma unroll
    for (int i = 0; i < 4; ++i) {
      const float* pa = (const float*)g.A + aoffE[i] + k0;
      ra[i][0] = *(const float4*)pa;
      ra[i][1] = *(const float4*)(pa + 4);
      int kb = k0 + cswz * 8;
      if (bok[i]) {
        const float* pb;
        if (g.B2 && kb >= g.kcut)
          pb = (const float*)g.B2 + (long)brow[i] * g.ldb2 + (kb - g.kcut);
        else
          pb = (const float*)g.B + (long)brow[i] * g.ldb + kb;
        rb[i][0] = *(const float4*)pb;
        rb[i][1] = *(const float4*)(pb + 4);
      } else {
        rb[i][0] = float4{0.f, 0.f, 0.f, 0.f};
        rb[i][1] = float4{0.f, 0.f, 0.f, 0.f};
      }
    }
  };
  auto writeR = [&](int buf) {
    #pragma unroll
    for (int i = 0; i < 4; ++i) {
      uint4 va, vb;
      va.x = pk2(ra[i][0].x, ra[i][0].y); va.y = pk2(ra[i][0].z, ra[i][0].w);
      va.z = pk2(ra[i][1].x, ra[i][1].y); va.w = pk2(ra[i][1].z, ra[i][1].w);
      vb.x = pk2(rb[i][0].x, rb[i][0].y); vb.y = pk2(rb[i][0].z, rb[i][0].w);
      vb.z = pk2(rb[i][1].x, rb[i][1].y); vb.w = pk2(rb[i][1].z, rb[i][1].w);
      *(uint4*)&lds[buf][dstA + i * 4096] = va;
      *(uint4*)&lds[buf][16384 + dstA + i * 4096] = vb;
    }
  };
  auto stageD = [&](int buf, int k0) {
    #pragma unroll
    for (int i = 0; i < 4; ++i) {
      gload_lds16((const uint16_t*)g.A + aoffE[i] + k0, &lds[buf][dstA + i * 4096]);
      gload_lds16((const uint16_t*)g.B + (long)brow[i] * g.ldb + cswz * 8 + k0,
                  &lds[buf][16384 + dstA + i * 4096]);
    }
  };
  auto compute = [&](int buf) {
    short8 af[4][2], bfr[4][2];
    #pragma unroll
    for (int q = 0; q < 4; ++q) {
      af[q][0] = *(const short8*)&lds[buf][raddr[q][0]];
      af[q][1] = *(const short8*)&lds[buf][raddr[q][1]];
      bfr[q][0] = *(const short8*)&lds[buf][baddr[q][0]];
      bfr[q][1] = *(const short8*)&lds[buf][baddr[q][1]];
    }
    #pragma unroll
    for (int mi = 0; mi < 4; ++mi)
      #pragma unroll
      for (int ni = 0; ni < 4; ++ni) {
        acc[mi][ni] = __builtin_amdgcn_mfma_f32_16x16x32_bf16(
            af[mi][0], bfr[ni][0], acc[mi][ni], 0, 0, 0);
        acc[mi][ni] = __builtin_amdgcn_mfma_f32_16x16x32_bf16(
            af[mi][1], bfr[ni][1], acc[mi][ni], 0, 0, 0);
      }
  };

  int cur = 0;
  if (STG == 1) {
    stageD(0, 0);
    __syncthreads();
    for (int t = 0; t < nt; ++t) {
      if (t + 1 < nt) stageD(cur ^ 1, (t + 1) << 6);
      compute(cur);
      __syncthreads();
      cur ^= 1;
    }
  } else {
    loadR(0); writeR(0);
    __syncthreads();
    for (int t = 0; t < nt; ++t) {
      if (t + 1 < nt) loadR((t + 1) << 6);
      compute(cur);
      if (t + 1 < nt) writeR(cur ^ 1);
      __syncthreads();
      cur ^= 1;
    }
  }

  if (EPI == 2) {
    #pragma unroll
    for (int mi = 0; mi < 4; ++mi) {
      #pragma unroll
      for (int r = 0; r < 4; ++r) {
        int grow = m0 + wm + mi * 16 + lg * 4 + r;
        int bb = grow / g.tdE;
        float s = 0.f;
        #pragma unroll
        for (int ni = 0; ni < 4; ++ni) {
          int col = n0 + wn + ni * 16 + l15;
          float val = acc[mi][ni][r] + g.v1[(long)bb * g.ldv1 + col];
          s += tanhf(val) * g.w2[col];
        }
        s += __shfl_xor(s, 1, 16);
        s += __shfl_xor(s, 2, 16);
        s += __shfl_xor(s, 4, 16);
        s += __shfl_xor(s, 8, 16);
        if (l15 == 0) atomicAdd(g.score + grow, s);
      }
    }
  } else {
    #pragma unroll
    for (int mi = 0; mi < 4; ++mi)
      #pragma unroll
      for (int ni = 0; ni < 4; ++ni)
        #pragma unroll
        for (int r = 0; r < 4; ++r) {
          int col = n0 + wn + ni * 16 + l15;
          if (col < g.N) {
            int grow = m0 + wm + mi * 16 + lg * 4 + r;
            float v = acc[mi][ni][r];
            if (g.bias) v += g.bias[col];
            if (g.bias2) v += g.bias2[col];
            g.C[(long)grow * g.ldc + g.coff + col] = v;
          }
        }
  }
}

// ---------------- softmax over T + weighted sum, D-split + z-batched --------
template<bool BF>
__global__ __launch_bounds__(256) void softmax_ctx2(
    const float* sc0, const float* sc1, const void* s0, const void* s1,
    float* o0, float* o1, int Tdim, long sB, long sT)
{
  __shared__ float exs[128], e2[128];
  int b = blockIdx.x, tid = threadIdx.x;
  const float* sc = blockIdx.z ? sc1 : sc0;
  const void* src = blockIdx.z ? s1 : s0;
  float* out = blockIdx.z ? o1 : o0;
  if (tid < Tdim) exs[tid] = sc[(long)b * Tdim + tid];
  __syncthreads();
  float mx = -1e30f;
  for (int t = 0; t < Tdim; ++t) mx = fmaxf(mx, exs[t]);
  if (tid < Tdim) e2[tid] = expf(exs[tid] - mx);
  __syncthreads();
  float sum = 0.f;
  for (int t = 0; t < Tdim; ++t) sum += e2[t];
  float inv = 1.f / sum;
  int col = blockIdx.y * 256 + tid;
  float acc = 0.f;
  for (int t = 0; t < Tdim; ++t) {
    float v;
    if (BF) v = bf2f(((const uint16_t*)src)[(long)b * sB + (long)t * sT + col]);
    else    v = ((const float*)src)[(long)b * sB + (long)t * sT + col];
    acc += e2[t] * v;
  }
  out[(long)b * 1024 + col] = acc * inv;
}

// ---------------- final attention (T=3) + x = [fc, input, hidden] -----------
__global__ __launch_bounds__(256) void final_ctx_x(
    const float* __restrict__ s3, const float* __restrict__ cs,
    const float* __restrict__ input, const float* __restrict__ hid,
    float* __restrict__ ofc, float* __restrict__ x)
{
  int b = blockIdx.x, tid = threadIdx.x;
  float s0 = s3[b * 3], s1 = s3[b * 3 + 1], s2 = s3[b * 3 + 2];
  float mx = fmaxf(s0, fmaxf(s1, s2));
  float e0 = expf(s0 - mx), e1 = expf(s1 - mx), e2 = expf(s2 - mx);
  float inv = 1.f / (e0 + e1 + e2);
  e0 *= inv; e1 *= inv; e2 *= inv;
  if (tid < 128) {
    int d = tid * 4;
    const float* c = cs + (long)b * 1536 + d;
    float4 v0 = *(const float4*)(c);
    float4 v1 = *(const float4*)(c + 512);
    float4 v2 = *(const float4*)(c + 1024);
    float4 r;
    r.x = e0 * v0.x + e1 * v1.x + e2 * v2.x;
    r.y = e0 * v0.y + e1 * v1.y + e2 * v2.y;
    r.z = e0 * v0.z + e1 * v1.z + e2 * v2.z;
    r.w = e0 * v0.w + e1 * v1.w + e2 * v2.w;
    *(float4*)&ofc[(long)b * 512 + d] = r;
    *(float4*)&x[(long)b * 2560 + d] = r;
  }
  int d2 = tid * 4;
  *(float4*)&x[(long)b * 2560 + 512 + d2] = *(const float4*)&input[(long)b * 1024 + d2];
  *(float4*)&x[(long)b * 2560 + 1536 + d2] = *(const float4*)&hid[(long)b * 1024 + d2];
}

// ---------------- LSTM pointwise --------------------------------------------
__global__ __launch_bounds__(256) void lstm_kernel(
    const float* __restrict__ gates, const float* __restrict__ cprev,
    float* __restrict__ hout, float* __restrict__ cout,
    float* __restrict__ hws)
{
  int idx = blockIdx.x * 256 + threadIdx.x;
  int b = idx >> 10, jj = idx & 1023;
  const float* gp = gates + (long)b * 4096;
  float gi = gp[jj], gf = gp[1024 + jj], gg = gp[2048 + jj], go = gp[3072 + jj];
  float i = 1.f / (1.f + expf(-gi));
  float f = 1.f / (1.f + expf(-gf));
  float t = tanhf(gg);
  float o = 1.f / (1.f + expf(-go));
  float c = f * cprev[idx] + i * t;
  float h = o * tanhf(c);
  hout[idx] = h; cout[idx] = c; hws[idx] = h;
}

// ---------------- host ------------------------------------------------------
extern "C" void kernel_launch(void* const* d_in, const int* in_sizes, int n_in,
                              void* d_out, int out_size, void* d_ws, size_t ws_size,
                              hipStream_t stream) {
  const float* input   = (const float*)d_in[0];
  const float* visual  = (const float*)d_in[1];
  const float* audio   = (const float*)d_in[2];
  const float* hstates = (const float*)d_in[3];
  const float* cell    = (const float*)d_in[4];
  const float* ctxq    = (const float*)d_in[5];
  const float* Wv0 = (const float*)d_in[6],  *Wv1 = (const float*)d_in[7],  *Wv2 = (const float*)d_in[8];
  const float* Wa0 = (const float*)d_in[9],  *Wa1 = (const float*)d_in[10], *Wa2 = (const float*)d_in[11];
  const float* Wh0 = (const float*)d_in[12], *Wh1 = (const float*)d_in[13], *Wh2 = (const float*)d_in[14];
  const float* Wc0 = (const float*)d_in[15], *Wc1 = (const float*)d_in[16], *Wc2 = (const float*)d_in[17];
  const float* Wac = (const float*)d_in[18], *bac = (const float*)d_in[19];
  const float* Wvc = (const float*)d_in[20], *bvc = (const float*)d_in[21];
  const float* Whc = (const float*)d_in[22], *bhc = (const float*)d_in[23];
  const float* W_ih = (const float*)d_in[24], *W_hh = (const float*)d_in[25];
  const float* b_ih = (const float*)d_in[26], *b_hh = (const float*)d_in[27];
  const float* W_out = (const float*)d_in[28], *b_out = (const float*)d_in[29];

  float* out = (float*)d_out;
  const long OFF_H = 2560000, OFF_C = 2691072, OFF_FC = 2822144;

  char* cur = (char*)d_ws;
  auto alloc = [&](size_t n) { char* p = cur; cur += (n + 255) & ~(size_t)255; return p; };
  float* scoreV = (float*)alloc(16384 * 4);
  float* scoreA = (float*)alloc(16384 * 4);
  float* scoreH = (float*)alloc(2048 * 4);
  float* scoreC = (float*)alloc(384 * 4);
  float* v1v  = (float*)alloc(128 * 1024 * 4);
  float* v1a  = (float*)alloc(128 * 1024 * 4);
  float* v1h  = (float*)alloc(128 * 1024 * 4);
  float* ctxV = (float*)alloc(128 * 1024 * 4);
  float* ctxA = (float*)alloc(128 * 1024 * 4);
  float* ctxH = (float*)alloc(128 * 1024 * 4);
  float* cstack = (float*)alloc(128 * 3 * 512 * 4);
  float* v1c  = (float*)alloc(128 * 512 * 4);
  float* xbuf = (float*)alloc(128 * 2560 * 4);
  float* gates = (float*)alloc(128 * 4096 * 4);
  float* hnew = (float*)alloc(128 * 1024 * 4);
  size_t small_used = (size_t)(cur - (char*)d_ws);
  size_t big_need = (size_t)(16777216 + 16777216 + 2097152 + 1048576 * 3) * 2 + 4096;
  bool big = ws_size >= small_used + big_need;
  uint16_t *visB = nullptr, *audB = nullptr, *hsB = nullptr,
           *wv1B = nullptr, *wa1B = nullptr, *wh1B = nullptr;
  if (big) {
    visB = (uint16_t*)alloc(16777216 * 2);
    audB = (uint16_t*)alloc(16777216 * 2);
    hsB  = (uint16_t*)alloc(2097152 * 2);
    wv1B = (uint16_t*)alloc(1048576 * 2);
    wa1B = (uint16_t*)alloc(1048576 * 2);
    wh1B = (uint16_t*)alloc(1048576 * 2);
  }

  if (big) {
    CvtBatch cb;
    cb.in[0] = visual; cb.out[0] = visB;
    cb.in[1] = audio;  cb.out[1] = audB;
    cb.in[2] = hstates; cb.out[2] = hsB;
    cb.in[3] = Wv1; cb.out[3] = wv1B;
    cb.in[4] = Wa1; cb.out[4] = wa1B;
    cb.in[5] = Wh1; cb.out[5] = wh1B;
    long n8[6] = {2097152, 2097152, 262144, 131072, 131072, 131072};
    long c = 0;
    for (int i = 0; i < 6; ++i) { cb.cum[i] = c; c += n8[i]; }
    cb.cum[6] = c;
    cvt_multi<<<2048, 256, 0, stream>>>(cb, c);
  }
  hipMemsetAsync(scoreV, 0, (16384 + 16384 + 2048 + 384) * 4, stream);

  auto D = [](const void* A, const void* B, float* C, int N, int K,
              const float* bias, int ldc, int coff, int tdA, long asB, long asT,
              int ldb) {
    GemmDesc d{};
    d.A = A; d.B = B; d.B2 = nullptr; d.C = C; d.bias = bias; d.bias2 = nullptr;
    d.v1 = nullptr; d.w2 = nullptr; d.score = nullptr;
    d.N = N; d.K = K; d.kcut = 1 << 30; d.ldb = ldb; d.ldb2 = 0;
    d.ldc = ldc; d.coff = coff; d.ldv1 = 0; d.tdE = 1; d.tdA = tdA;
    d.asB = asB; d.asT = asT;
    return d;
  };

  // v1 triple: [128,512] @ [1024,512]^T
  {
    GemmBatch bt{};
    bt.d[0] = D(ctxq, Wv0, v1v, 1024, 512, nullptr, 1024, 0, 1, 512, 0, 512);
    bt.d[1] = D(ctxq, Wa0, v1a, 1024, 512, nullptr, 1024, 0, 1, 512, 0, 512);
    bt.d[2] = D(ctxq, Wh0, v1h, 1024, 512, nullptr, 1024, 0, 1, 512, 0, 512);
    gemm2<0, 0><<<dim3(8, 1, 3), 256, 0, stream>>>(bt);
  }

  // fused score GEMMs
  if (big) {
    GemmBatch bt{};
    bt.d[0] = D(visB, wv1B, nullptr, 1024, 1024, nullptr, 0, 0, 1, 1024, 0, 1024);
    bt.d[0].v1 = v1v; bt.d[0].w2 = Wv2; bt.d[0].score = scoreV; bt.d[0].tdE = 128; bt.d[0].ldv1 = 1024;
    bt.d[1] = D(audB, wa1B, nullptr, 1024, 1024, nullptr, 0, 0, 1, 1024, 0, 1024);
    bt.d[1].v1 = v1a; bt.d[1].w2 = Wa2; bt.d[1].score = scoreA; bt.d[1].tdE = 128; bt.d[1].ldv1 = 1024;
    gemm2<2, 1><<<dim3(8, 128, 2), 256, 0, stream>>>(bt);
    GemmBatch bh{};
    bh.d[0] = D(hsB, wh1B, nullptr, 1024, 1024, nullptr, 0, 0, 16, 1024, 131072, 1024);
    bh.d[0].v1 = v1h; bh.d[0].w2 = Wh2; bh.d[0].score = scoreH; bh.d[0].tdE = 16; bh.d[0].ldv1 = 1024;
    gemm2<2, 1><<<dim3(8, 16, 1), 256, 0, stream>>>(bh);
  } else {
    GemmBatch bt{};
    bt.d[0] = D(visual, Wv1, nullptr, 1024, 1024, nullptr, 0, 0, 1, 1024, 0, 1024);
    bt.d[0].v1 = v1v; bt.d[0].w2 = Wv2; bt.d[0].score = scoreV; bt.d[0].tdE = 128; bt.d[0].ldv1 = 1024;
    bt.d[1] = D(audio, Wa1, nullptr, 1024, 1024, nullptr, 0, 0, 1, 1024, 0, 1024);
    bt.d[1].v1 = v1a; bt.d[1].w2 = Wa2; bt.d[1].score = scoreA; bt.d[1].tdE = 128; bt.d[1].ldv1 = 1024;
    gemm2<2, 0><<<dim3(8, 128, 2), 256, 0, stream>>>(bt);
    GemmBatch bh{};
    bh.d[0] = D(hstates, Wh1, nullptr, 1024, 1024, nullptr, 0, 0, 16, 1024, 131072, 1024);
    bh.d[0].v1 = v1h; bh.d[0].w2 = Wh2; bh.d[0].score = scoreH; bh.d[0].tdE = 16; bh.d[0].ldv1 = 1024;
    gemm2<2, 0><<<dim3(8, 16, 1), 256, 0, stream>>>(bh);
  }

  // softmax + weighted context
  if (big)
    softmax_ctx2<true><<<dim3(128, 4, 2), 256, 0, stream>>>(
        scoreV, scoreA, visB, audB, ctxV, ctxA, 128, 131072, 1024);
  else
    softmax_ctx2<false><<<dim3(128, 4, 2), 256, 0, stream>>>(
        scoreV, scoreA, visual, audio, ctxV, ctxA, 128, 131072, 1024);
  softmax_ctx2<false><<<dim3(128, 4, 1), 256, 0, stream>>>(
      scoreH, nullptr, hstates, nullptr, ctxH, nullptr, 16, 1024, 131072);

  // cstack triple: [128,1024] @ [512,1024]^T + bias
  {
    GemmBatch bt{};
    bt.d[0] = D(ctxA, Wac, cstack, 512, 1024, bac, 1536, 0, 1, 1024, 0, 1024);
    bt.d[1] = D(ctxV, Wvc, cstack, 512, 1024, bvc, 1536, 512, 1, 1024, 0, 1024);
    bt.d[2] = D(ctxH, Whc, cstack, 512, 1024, bhc, 1536, 1024, 1, 1024, 0, 1024);
    gemm2<0, 0><<<dim3(4, 1, 3), 256, 0, stream>>>(bt);
  }

  const float* hid_last = hstates + (long)15 * 128 * 1024;
  // v1c = hidden @ Wc0^T
  {
    GemmBatch bt{};
    bt.d[0] = D(hid_last, Wc0, v1c, 512, 1024, nullptr, 512, 0, 1, 1024, 0, 1024);
    gemm2<0, 0><<<dim3(4, 1, 1), 256, 0, stream>>>(bt);
  }
  // scoreC (384 rows of cstack)
  {
    GemmBatch bt{};
    bt.d[0] = D(cstack, Wc1, nullptr, 512, 512, nullptr, 0, 0, 1, 512, 0, 512);
    bt.d[0].v1 = v1c; bt.d[0].w2 = Wc2; bt.d[0].score = scoreC; bt.d[0].tdE = 3; bt.d[0].ldv1 = 512;
    gemm2<2, 0><<<dim3(4, 3, 1), 256, 0, stream>>>(bt);
  }
  final_ctx_x<<<128, 256, 0, stream>>>(scoreC, cstack, input, hid_last, out + OFF_FC, xbuf);

  // gates = [fc,input,hidden] @ [W_ih|W_hh]^T + b_ih + b_hh  (K=2560)
  {
    GemmBatch bt{};
    bt.d[0] = D(xbuf, W_ih, gates, 4096, 2560, b_ih, 4096, 0, 1, 2560, 0, 1536);
    bt.d[0].B2 = W_hh; bt.d[0].ldb2 = 1024; bt.d[0].kcut = 1536; bt.d[0].bias2 = b_hh;
    gemm2<0, 0><<<dim3(32, 1, 1), 256, 0, stream>>>(bt);
  }
  lstm_kernel<<<512, 256, 0, stream>>>(gates, cell, out + OFF_H, out + OFF_C, hnew);

  // logits
  {
    GemmBatch bt{};
    bt.d[0] = D(hnew, W_out, out, 20000, 1024, b_out, 20000, 0, 1, 1024, 0, 1024);
    gemm2<0, 0><<<dim3(157, 1, 1), 256, 0, stream>>>(bt);
  }

  (void)in_sizes; (void)n_in; (void)out_size;
}